// Round 2
// baseline (175.682 us; speedup 1.0000x reference)
//
#include <hip/hip_runtime.h>

typedef short bf16x8 __attribute__((ext_vector_type(8)));
typedef float f32x4 __attribute__((ext_vector_type(4)));
typedef unsigned short u16;
typedef unsigned int u32;

#define DEVI static __device__ __forceinline__

// Problem constants
#define NB 16
#define NS 2048
#define NW 768
#define NH 64

DEVI u16 f2bf(float x) {
  u32 u = __builtin_bit_cast(u32, x);
  u += 0x7fffu + ((u >> 16) & 1u);
  return (u16)(u >> 16);
}

DEVI f32x4 mfma16(bf16x8 a, bf16x8 b, f32x4 c) {
  return __builtin_amdgcn_mfma_f32_16x16x32_bf16(a, b, c, 0, 0, 0);
}

// XOR swizzle for width-64-bf16 LDS tiles: breaks the 128B-row-stride bank conflict.
DEVI int swz(int row, int col) { return ((row * 64 + col) * 2) ^ ((row & 7) << 4); }

// ---------------------------------------------------------------------------
// Kernel 0: rearrange Wq/Wk/Wv (fp32 [768][64]) into bf16 MFMA-B-fragment order.
// Tile (p, nct, kch): 16 cols x 32 k; lane*16B = that lane's B-fragment:
// k = kch*32 + (lane>>4)*8 + i, n = nct*16 + (lane&15).  288 tiles * 1KB.
// ---------------------------------------------------------------------------
__global__ __launch_bounds__(256) void prep_weights(
    const float* __restrict__ Wq, const float* __restrict__ Wk,
    const float* __restrict__ Wv, u16* __restrict__ wsW) {
  int tid = blockIdx.x * 256 + threadIdx.x;
  int tile = tid >> 6, lane = tid & 63;
  int p = tile / 96, rem = tile % 96;
  int nct = rem / 24, kch = rem % 24;
  const float* Wsrc = (p == 0) ? Wq : ((p == 1) ? Wk : Wv);
  int k0 = kch * 32 + (lane >> 4) * 8;
  int n = nct * 16 + (lane & 15);
  u16 h[8];
#pragma unroll
  for (int i = 0; i < 8; i++) h[i] = f2bf(Wsrc[(k0 + i) * NH + n]);
  uint4 v;
  v.x = (u32)h[0] | ((u32)h[1] << 16);
  v.y = (u32)h[2] | ((u32)h[3] << 16);
  v.z = (u32)h[4] | ((u32)h[5] << 16);
  v.w = (u32)h[6] | ((u32)h[7] << 16);
  ((uint4*)wsW)[tile * 64 + lane] = v;
}

// ---------------------------------------------------------------------------
// Kernel 1: fused QKV projection. BM=64 rows/block, 4 waves x 16 rows.
// A staged in swizzled LDS; W fragments read directly from wsW (L1/L2-hit).
// Writes Q,K as bf16 [b][s][64]; V transposed as bf16 [b][64][s].
// ---------------------------------------------------------------------------
__global__ __launch_bounds__(256) void qkv_proj(
    const float* __restrict__ inp, const u16* __restrict__ wsW,
    const float* __restrict__ bq, const float* __restrict__ bk,
    const float* __restrict__ bv, u16* __restrict__ Q, u16* __restrict__ K,
    u16* __restrict__ Vt) {
  __shared__ __align__(16) u16 A_lds[64 * 64];  // 8 KB, swizzled
  int tid = threadIdx.x;
  int w = tid >> 6, lane = tid & 63, g = lane >> 4, l15 = lane & 15;
  int row0 = blockIdx.x * 64;

  f32x4 acc[12];
#pragma unroll
  for (int ct = 0; ct < 12; ct++) acc[ct] = (f32x4)0.0f;

  for (int chunk = 0; chunk < 12; chunk++) {
    int k0 = chunk * 64;
    __syncthreads();  // protect previous iteration's reads
    // Stage A: input[row0..+64][k0..+64] fp32 -> bf16 swizzled LDS
#pragma unroll
    for (int p = 0; p < 4; p++) {
      int id = tid + p * 256;
      int r = id >> 4, c4 = (id & 15) * 4;
      const float4 v =
          *(const float4*)(inp + (size_t)(row0 + r) * NW + k0 + c4);
      ushort4 h4;
      h4.x = f2bf(v.x); h4.y = f2bf(v.y); h4.z = f2bf(v.z); h4.w = f2bf(v.w);
      *(ushort4*)((char*)A_lds + swz(r, c4)) = h4;
    }
    __syncthreads();
    // A fragments for this wave's 16 rows
    bf16x8 af[2];
#pragma unroll
    for (int kk = 0; kk < 2; kk++)
      af[kk] =
          *(const bf16x8*)((const char*)A_lds + swz(w * 16 + l15, kk * 32 + g * 8));
    // W fragments direct from global (frag-ordered; all waves same addr -> L1)
#pragma unroll
    for (int ct = 0; ct < 12; ct++)
#pragma unroll
      for (int kk = 0; kk < 2; kk++) {
        bf16x8 bfr = *(const bf16x8*)(wsW +
                                      (size_t)(ct * 24 + chunk * 2 + kk) * 512 +
                                      lane * 8);
        acc[ct] = mfma16(af[kk], bfr, acc[ct]);
      }
  }

  // Epilogue: add bias, store bf16. Q/K row-major; V transposed [b][h][s].
  int b = row0 >> 11, s0b = row0 & 2047;
  int srow = s0b + w * 16 + g * 4;
#pragma unroll
  for (int ct = 0; ct < 12; ct++) {
    int p3 = ct >> 2, n = (ct & 3) * 16 + l15;
    const float* bias = (p3 == 0) ? bq : ((p3 == 1) ? bk : bv);
    float bb = bias[n];
    if (p3 == 0) {
      u16* dst = Q + ((size_t)(b * NS + srow) * NH + n);
#pragma unroll
      for (int reg = 0; reg < 4; reg++)
        dst[(size_t)reg * NH] = f2bf(acc[ct][reg] + bb);
    } else if (p3 == 1) {
      u16* dst = K + ((size_t)(b * NS + srow) * NH + n);
#pragma unroll
      for (int reg = 0; reg < 4; reg++)
        dst[(size_t)reg * NH] = f2bf(acc[ct][reg] + bb);
    } else {
      ushort4 h4;
      h4.x = f2bf(acc[ct][0] + bb);
      h4.y = f2bf(acc[ct][1] + bb);
      h4.z = f2bf(acc[ct][2] + bb);
      h4.w = f2bf(acc[ct][3] + bb);
      *(ushort4*)(Vt + (size_t)b * NH * NS + (size_t)n * NS + srow) = h4;
    }
  }
}

// ---------------------------------------------------------------------------
// Kernel 2: flash attention, barrier-free main loop.
// Block: (32 q-rows, batch b); 4 waves each own a 512-key chunk (in-block
// KV-split) with private online-softmax state. K/V fragments read straight
// from global (L1/L2-resident); P via wave-private LDS (no barriers).
// End: one barrier, LDS merge of the 4 partials, normalized fp32 store.
// ---------------------------------------------------------------------------
__global__ __launch_bounds__(256) void attn(
    const u16* __restrict__ Q, const u16* __restrict__ K,
    const u16* __restrict__ Vt, const int* __restrict__ mask,
    float* __restrict__ out) {
  // Phase 1: 4 x 4KB wave-private P tiles. Phase 2 (after barrier): aliased
  // as accL[4][32][65] f32 (33280B) + mlL[4][32][2] f32 (1024B).
  __shared__ __align__(16) char smem[34304];
  int tid = threadIdx.x;
  int w = tid >> 6, lane = tid & 63, g = lane >> 4, l15 = lane & 15;
  int q0 = blockIdx.x * 32;
  int b = blockIdx.y;
  const u16* Qb = Q + (size_t)b * NS * NH;
  const u16* Kb = K + (size_t)b * NS * NH;
  const u16* Vb = Vt + (size_t)b * NH * NS;
  const int* mb = mask + b * NS;
  u16* Pw = (u16*)(smem + w * 4096);

  // Q fragments (all 4 waves load the same 32 rows -> L1 broadcast)
  bf16x8 qf[2][2];
#pragma unroll
  for (int rt = 0; rt < 2; rt++)
#pragma unroll
    for (int kk = 0; kk < 2; kk++)
      qf[rt][kk] = *(const bf16x8*)(Qb + (size_t)(q0 + rt * 16 + l15) * NH +
                                    kk * 32 + g * 8);

  f32x4 acc[2][4];
  float m_run[2][4], l_run[2][4];
#pragma unroll
  for (int rt = 0; rt < 2; rt++) {
#pragma unroll
    for (int ht = 0; ht < 4; ht++) acc[rt][ht] = (f32x4)0.0f;
#pragma unroll
    for (int reg = 0; reg < 4; reg++) {
      m_run[rt][reg] = -3.0e38f;
      l_run[rt][reg] = 0.0f;
    }
  }

  // This wave's 8 KV tiles (512 keys)
  for (int t = w * 8; t < w * 8 + 8; t++) {
    int kv0 = t * 64;
    int mv[4];
#pragma unroll
    for (int ct = 0; ct < 4; ct++) mv[ct] = mb[kv0 + ct * 16 + l15];

    // S = Q K^T : K fragments direct from global
    f32x4 sf[2][4];
#pragma unroll
    for (int rt = 0; rt < 2; rt++)
#pragma unroll
      for (int ct = 0; ct < 4; ct++) sf[rt][ct] = (f32x4)0.0f;
#pragma unroll
    for (int ct = 0; ct < 4; ct++)
#pragma unroll
      for (int kk = 0; kk < 2; kk++) {
        bf16x8 kf = *(const bf16x8*)(Kb +
                                     (size_t)(kv0 + ct * 16 + l15) * NH +
                                     kk * 32 + g * 8);
        sf[0][ct] = mfma16(qf[0][kk], kf, sf[0][ct]);
        sf[1][ct] = mfma16(qf[1][kk], kf, sf[1][ct]);
      }

    // Online softmax (row stats live in the 16 lanes sharing g)
#pragma unroll
    for (int rt = 0; rt < 2; rt++) {
      float pr[4][4], tm[4];
#pragma unroll
      for (int reg = 0; reg < 4; reg++) tm[reg] = -3.0e38f;
#pragma unroll
      for (int ct = 0; ct < 4; ct++)
#pragma unroll
        for (int reg = 0; reg < 4; reg++) {
          float sv = sf[rt][ct][reg] * 0.125f;  // 1/sqrt(64)
          pr[ct][reg] = sv;
          if (mv[ct]) tm[reg] = fmaxf(tm[reg], sv);
        }
#pragma unroll
      for (int o = 1; o < 16; o <<= 1)
#pragma unroll
        for (int reg = 0; reg < 4; reg++)
          tm[reg] = fmaxf(tm[reg], __shfl_xor(tm[reg], o, 64));
      float corr[4], rs[4];
#pragma unroll
      for (int reg = 0; reg < 4; reg++) {
        float mn = fmaxf(m_run[rt][reg], tm[reg]);
        corr[reg] = __expf(m_run[rt][reg] - mn);
        m_run[rt][reg] = mn;
        rs[reg] = 0.0f;
      }
#pragma unroll
      for (int ct = 0; ct < 4; ct++)
#pragma unroll
        for (int reg = 0; reg < 4; reg++) {
          float p = mv[ct] ? __expf(pr[ct][reg] - m_run[rt][reg]) : 0.0f;
          pr[ct][reg] = p;
          rs[reg] += p;
        }
#pragma unroll
      for (int o = 1; o < 16; o <<= 1)
#pragma unroll
        for (int reg = 0; reg < 4; reg++) rs[reg] += __shfl_xor(rs[reg], o, 64);
#pragma unroll
      for (int reg = 0; reg < 4; reg++)
        l_run[rt][reg] = l_run[rt][reg] * corr[reg] + rs[reg];
#pragma unroll
      for (int ht = 0; ht < 4; ht++)
#pragma unroll
        for (int reg = 0; reg < 4; reg++) acc[rt][ht][reg] *= corr[reg];
      // P (bf16) -> wave-private LDS for re-fragmentation (no barrier needed)
#pragma unroll
      for (int ct = 0; ct < 4; ct++)
#pragma unroll
        for (int reg = 0; reg < 4; reg++) {
          int q = rt * 16 + g * 4 + reg;
          int c = ct * 16 + l15;
          *(u16*)((char*)Pw + swz(q, c)) = f2bf(pr[ct][reg]);
        }
    }

    // O += P V : V fragments direct from global (Vt is [b][h][s])
#pragma unroll
    for (int ks = 0; ks < 2; ks++) {
      bf16x8 pf[2];
#pragma unroll
      for (int rt = 0; rt < 2; rt++)
        pf[rt] = *(const bf16x8*)((const char*)Pw +
                                  swz(rt * 16 + l15, ks * 32 + g * 8));
#pragma unroll
      for (int ht = 0; ht < 4; ht++) {
        bf16x8 vf = *(const bf16x8*)(Vb + (size_t)(ht * 16 + l15) * NS + kv0 +
                                     ks * 32 + g * 8);
        acc[0][ht] = mfma16(pf[0], vf, acc[0][ht]);
        acc[1][ht] = mfma16(pf[1], vf, acc[1][ht]);
      }
    }
  }

  // Merge the 4 KV-chunk partials via LDS
  __syncthreads();  // all P-tiles dead; alias smem as accL/mlL
  float* accL = (float*)smem;                 // [z][row][65] padded
  float* mlL = (float*)(smem + 33280);        // [z][row][2]
#pragma unroll
  for (int rt = 0; rt < 2; rt++) {
    int row = rt * 16 + g * 4;
#pragma unroll
    for (int ht = 0; ht < 4; ht++)
#pragma unroll
      for (int reg = 0; reg < 4; reg++)
        accL[(w * 32 + row + reg) * 65 + ht * 16 + l15] = acc[rt][ht][reg];
    if (l15 == 0) {
#pragma unroll
      for (int reg = 0; reg < 4; reg++) {
        mlL[(w * 32 + row + reg) * 2 + 0] = m_run[rt][reg];
        mlL[(w * 32 + row + reg) * 2 + 1] = l_run[rt][reg];
      }
    }
  }
  __syncthreads();

#pragma unroll
  for (int i = 0; i < 8; i++) {
    int idx = tid + i * 256;  // 0..2047
    int row = idx >> 6, h = idx & 63;
    float m[4], l[4];
#pragma unroll
    for (int z = 0; z < 4; z++) {
      m[z] = mlL[(z * 32 + row) * 2 + 0];
      l[z] = mlL[(z * 32 + row) * 2 + 1];
    }
    float M = fmaxf(fmaxf(m[0], m[1]), fmaxf(m[2], m[3]));
    float den = 0.0f, o = 0.0f;
#pragma unroll
    for (int z = 0; z < 4; z++) {
      float e = __expf(m[z] - M);
      den += e * l[z];
      o += e * accL[(z * 32 + row) * 65 + h];
    }
    out[((size_t)b * NS + q0 + row) * NH + h] = o / den;
  }
}

extern "C" void kernel_launch(void* const* d_in, const int* in_sizes, int n_in,
                              void* d_out, int out_size, void* d_ws,
                              size_t ws_size, hipStream_t stream) {
  const float* inp = (const float*)d_in[0];
  const int* mask = (const int*)d_in[1];
  const float* Wq = (const float*)d_in[2];
  const float* bq = (const float*)d_in[3];
  const float* Wk = (const float*)d_in[4];
  const float* bk = (const float*)d_in[5];
  const float* Wv = (const float*)d_in[6];
  const float* bv = (const float*)d_in[7];
  float* out = (float*)d_out;

  char* ws = (char*)d_ws;
  u16* wsW = (u16*)ws;                          // 288 KB (frag-ordered weights)
  u16* wsQ = (u16*)(ws + (1u << 20));           // 4 MB
  u16* wsK = (u16*)(ws + (1u << 20) + (4u << 20));
  u16* wsVt = (u16*)(ws + (1u << 20) + (8u << 20));

  prep_weights<<<dim3(72), dim3(256), 0, stream>>>(Wq, Wk, Wv, wsW);
  qkv_proj<<<dim3((NB * NS) / 64), dim3(256), 0, stream>>>(inp, wsW, bq, bk, bv,
                                                           wsQ, wsK, wsVt);
  attn<<<dim3(NS / 32, NB), dim3(256), 0, stream>>>(wsQ, wsK, wsVt, mask, out);
}

// Round 3
// 124.101 us; speedup vs baseline: 1.4156x; 1.4156x over previous
//
#include <hip/hip_runtime.h>

typedef short bf16x8 __attribute__((ext_vector_type(8)));
typedef float f32x4 __attribute__((ext_vector_type(4)));
typedef unsigned short u16;
typedef unsigned int u32;

#define DEVI static __device__ __forceinline__

// Problem constants
#define NB 16
#define NS 2048
#define NW 768
#define NH 64

DEVI u16 f2bf(float x) {
  u32 u = __builtin_bit_cast(u32, x);
  u += 0x7fffu + ((u >> 16) & 1u);
  return (u16)(u >> 16);
}

DEVI u32 pkbf(float lo, float hi) {
  return (u32)f2bf(lo) | ((u32)f2bf(hi) << 16);
}

DEVI f32x4 mfma16(bf16x8 a, bf16x8 b, f32x4 c) {
  return __builtin_amdgcn_mfma_f32_16x16x32_bf16(a, b, c, 0, 0, 0);
}

// XOR swizzle for width-64-bf16 LDS tiles: breaks the 128B-row-stride bank conflict.
DEVI int swz(int row, int col) { return ((row * 64 + col) * 2) ^ ((row & 7) << 4); }

// ---------------------------------------------------------------------------
// Kernel 0: rearrange Wq/Wk/Wv (fp32 [768][64]) into bf16 MFMA-B-fragment order.
// Tile gct*24+kch (gct 0..11 col-tiles over [Q|K|V], kch 0..23): lane*16B holds
// k = kch*32 + (lane>>4)*8 + i, n = gct*16... (n within the 192-col concat).
// ---------------------------------------------------------------------------
__global__ __launch_bounds__(256) void prep_weights(
    const float* __restrict__ Wq, const float* __restrict__ Wk,
    const float* __restrict__ Wv, u16* __restrict__ wsW) {
  int tid = blockIdx.x * 256 + threadIdx.x;
  int tile = tid >> 6, lane = tid & 63;
  int p = tile / 96, rem = tile % 96;
  int nct = rem / 24, kch = rem % 24;
  const float* Wsrc = (p == 0) ? Wq : ((p == 1) ? Wk : Wv);
  int k0 = kch * 32 + (lane >> 4) * 8;
  int n = nct * 16 + (lane & 15);
  u16 h[8];
#pragma unroll
  for (int i = 0; i < 8; i++) h[i] = f2bf(Wsrc[(k0 + i) * NH + n]);
  uint4 v;
  v.x = (u32)h[0] | ((u32)h[1] << 16);
  v.y = (u32)h[2] | ((u32)h[3] << 16);
  v.z = (u32)h[4] | ((u32)h[5] << 16);
  v.w = (u32)h[6] | ((u32)h[7] << 16);
  ((uint4*)wsW)[tile * 64 + lane] = v;
}

// ---------------------------------------------------------------------------
// Kernel 1: fused QKV projection. BM=128, 8 waves (4 row x 2 col), grid 256.
// Register-prefetch pipeline: loads for chunk t+1 issued during chunk t's
// compute phase; single LDS buffer (A 16KB + W 24KB), 2 barriers/chunk.
// Writes Q,K as bf16 [b][s][64]; V transposed as bf16 [b][64][s].
// ---------------------------------------------------------------------------
__global__ __launch_bounds__(512) void qkv_proj(
    const float* __restrict__ inp, const u16* __restrict__ wsW,
    const float* __restrict__ bq, const float* __restrict__ bk,
    const float* __restrict__ bv, u16* __restrict__ Q, u16* __restrict__ K,
    u16* __restrict__ Vt) {
  __shared__ __align__(16) u16 A_lds[128 * 64];  // 16 KB, swizzled
  __shared__ __align__(16) u16 W_lds[24 * 512];  // 24 KB, frag-order tiles
  int tid = threadIdx.x;
  int w = tid >> 6, lane = tid & 63, g = lane >> 4, l15 = lane & 15;
  int wr = w & 3, wc = w >> 2;
  int row0 = blockIdx.x * 128;

  f32x4 acc[2][6];
#pragma unroll
  for (int rt = 0; rt < 2; rt++)
#pragma unroll
    for (int ct = 0; ct < 6; ct++) acc[rt][ct] = (f32x4)0.0f;

  float4 a_reg[4];
  uint4 w_reg[3];
  // Prefetch chunk 0
#pragma unroll
  for (int p = 0; p < 4; p++) {
    int id = tid + p * 512;
    int r = id >> 4, c4 = (id & 15) * 4;
    a_reg[p] = *(const float4*)(inp + (size_t)(row0 + r) * NW + c4);
  }
#pragma unroll
  for (int p = 0; p < 3; p++) {
    int id = tid + p * 512;
    int t = id >> 6, ls = id & 63;
    w_reg[p] = ((const uint4*)wsW)[((t >> 1) * 24 + (t & 1)) * 64 + ls];
  }

  for (int chunk = 0; chunk < 12; chunk++) {
    __syncthreads();  // previous compute done reading LDS
    // Write staged registers to LDS (vmcnt wait inserted by compiler)
#pragma unroll
    for (int p = 0; p < 4; p++) {
      int id = tid + p * 512;
      int r = id >> 4, c4 = (id & 15) * 4;
      float4 v = a_reg[p];
      ushort4 h4;
      h4.x = f2bf(v.x); h4.y = f2bf(v.y); h4.z = f2bf(v.z); h4.w = f2bf(v.w);
      *(ushort4*)((char*)A_lds + swz(r, c4)) = h4;
    }
#pragma unroll
    for (int p = 0; p < 3; p++) {
      int id = tid + p * 512;
      int t = id >> 6, ls = id & 63;
      ((uint4*)W_lds)[t * 64 + ls] = w_reg[p];
    }
    // Issue next chunk's loads (complete during this chunk's compute)
    if (chunk < 11) {
      int k0 = (chunk + 1) * 64;
#pragma unroll
      for (int p = 0; p < 4; p++) {
        int id = tid + p * 512;
        int r = id >> 4, c4 = (id & 15) * 4;
        a_reg[p] = *(const float4*)(inp + (size_t)(row0 + r) * NW + k0 + c4);
      }
#pragma unroll
      for (int p = 0; p < 3; p++) {
        int id = tid + p * 512;
        int t = id >> 6, ls = id & 63;
        w_reg[p] = ((const uint4*)
                        wsW)[((t >> 1) * 24 + (chunk + 1) * 2 + (t & 1)) * 64 + ls];
      }
    }
    __syncthreads();
    // Compute: this wave's 32 rows x 96 cols
    bf16x8 af[2][2];
#pragma unroll
    for (int rt = 0; rt < 2; rt++)
#pragma unroll
      for (int kk = 0; kk < 2; kk++)
        af[rt][kk] = *(const bf16x8*)((const char*)A_lds +
                                      swz(wr * 32 + rt * 16 + l15, kk * 32 + g * 8));
#pragma unroll
    for (int ct = 0; ct < 6; ct++)
#pragma unroll
      for (int kk = 0; kk < 2; kk++) {
        bf16x8 bfr = *(const bf16x8*)(W_lds +
                                      (((wc * 6 + ct) * 2 + kk) * 512 + lane * 8));
        acc[0][ct] = mfma16(af[0][kk], bfr, acc[0][ct]);
        acc[1][ct] = mfma16(af[1][kk], bfr, acc[1][ct]);
      }
  }

  // Epilogue: add bias, store bf16. Q/K row-major; V transposed [b][h][s].
  int b = row0 >> 11, s0b = row0 & 2047;
#pragma unroll
  for (int ct = 0; ct < 6; ct++) {
    int gct = wc * 6 + ct;
    int p3 = gct >> 2, n = (gct & 3) * 16 + l15;
    const float* bias = (p3 == 0) ? bq : ((p3 == 1) ? bk : bv);
    float bb = bias[n];
#pragma unroll
    for (int rt = 0; rt < 2; rt++) {
      int srow = s0b + wr * 32 + rt * 16 + g * 4;
      if (p3 == 0) {
        u16* dst = Q + ((size_t)(b * NS + srow) * NH + n);
#pragma unroll
        for (int reg = 0; reg < 4; reg++)
          dst[(size_t)reg * NH] = f2bf(acc[rt][ct][reg] + bb);
      } else if (p3 == 1) {
        u16* dst = K + ((size_t)(b * NS + srow) * NH + n);
#pragma unroll
        for (int reg = 0; reg < 4; reg++)
          dst[(size_t)reg * NH] = f2bf(acc[rt][ct][reg] + bb);
      } else {
        ushort4 h4;
        h4.x = f2bf(acc[rt][ct][0] + bb);
        h4.y = f2bf(acc[rt][ct][1] + bb);
        h4.z = f2bf(acc[rt][ct][2] + bb);
        h4.w = f2bf(acc[rt][ct][3] + bb);
        *(ushort4*)(Vt + (size_t)b * NH * NS + (size_t)n * NS + srow) = h4;
      }
    }
  }
}

// ---------------------------------------------------------------------------
// Kernel 2: flash attention with swapped QK^T (S^T = K Q^T).
// Block: (32 q-rows, batch b); 4 waves each own 512 keys (in-block KV-split).
// S^T puts each softmax row in 4 lanes -> row reduce = 2 shfl_xor.
// P packed to bf16 pairs, wave-private LDS (8B writes), read back as A-frags.
// exp2-domain softmax (native v_exp_f32). One barrier + merge at the end.
// ---------------------------------------------------------------------------
__global__ __launch_bounds__(256) void attn(
    const u16* __restrict__ Q, const u16* __restrict__ K,
    const u16* __restrict__ Vt, const int* __restrict__ mask,
    float* __restrict__ out) {
  // Phase 1: 4 x 4KB wave-private P tiles (32 q x 64 key bf16, swizzled).
  // Phase 2 (after barrier): accL[4][32][65] f32 + mlL[4][32][2] f32.
  __shared__ __align__(16) char smem[34304];
  int tid = threadIdx.x;
  int w = tid >> 6, lane = tid & 63, g = lane >> 4, l15 = lane & 15;
  int q0 = blockIdx.x * 32;
  int b = blockIdx.y;
  const u16* Qb = Q + (size_t)b * NS * NH;
  const u16* Kb = K + (size_t)b * NS * NH;
  const u16* Vb = Vt + (size_t)b * NH * NS;
  const int* mb = mask + b * NS;
  char* Pw = smem + w * 4096;

  const float SC = 0.18033688011112043f;  // log2(e)/sqrt(64)

  // Q fragments (B-operand; same lane->memory mapping as A-frag)
  bf16x8 qf[2][2];
#pragma unroll
  for (int rt = 0; rt < 2; rt++)
#pragma unroll
    for (int kk = 0; kk < 2; kk++)
      qf[rt][kk] = *(const bf16x8*)(Qb + (size_t)(q0 + rt * 16 + l15) * NH +
                                    kk * 32 + g * 8);

  f32x4 acc[2][4];
  float m_run[2], l_run[2];
#pragma unroll
  for (int rt = 0; rt < 2; rt++) {
#pragma unroll
    for (int ht = 0; ht < 4; ht++) acc[rt][ht] = (f32x4)0.0f;
    m_run[rt] = -3.0e38f;
    l_run[rt] = 0.0f;
  }

  // bpermute byte-addrs: src lane g*4+reg (holds corr for q-row g*4+reg)
  int corr_addr[4];
#pragma unroll
  for (int reg = 0; reg < 4; reg++) corr_addr[reg] = (lane & 48) + reg * 4;

  // This wave's 8 KV tiles (512 keys)
  for (int t = w * 8; t < w * 8 + 8; t++) {
    int kv0 = t * 64;
    // Hoisted loads: K A-frags + mask (independent, issued together)
    bf16x8 kf[4][2];
#pragma unroll
    for (int ct = 0; ct < 4; ct++)
#pragma unroll
      for (int kk = 0; kk < 2; kk++)
        kf[ct][kk] = *(const bf16x8*)(Kb + (size_t)(kv0 + ct * 16 + l15) * NH +
                                      kk * 32 + g * 8);
    int4 mv4[4];
#pragma unroll
    for (int ct = 0; ct < 4; ct++)
      mv4[ct] = *(const int4*)(mb + kv0 + ct * 16 + g * 4);

    // S^T = K Q^T : lane (g,l15) gets S[key=16ct+4g+reg][q=rt*16+l15]
    f32x4 sT[2][4];
#pragma unroll
    for (int rt = 0; rt < 2; rt++)
#pragma unroll
      for (int ct = 0; ct < 4; ct++) sT[rt][ct] = (f32x4)0.0f;
#pragma unroll
    for (int ct = 0; ct < 4; ct++)
#pragma unroll
      for (int kk = 0; kk < 2; kk++) {
        sT[0][ct] = mfma16(kf[ct][kk], qf[0][kk], sT[0][ct]);
        sT[1][ct] = mfma16(kf[ct][kk], qf[1][kk], sT[1][ct]);
      }

    // Online softmax (exp2 domain); each q-row lives in 4 lanes (same l15)
#pragma unroll
    for (int rt = 0; rt < 2; rt++) {
      float sv[4][4];
      float tm = -3.0e38f;
#pragma unroll
      for (int ct = 0; ct < 4; ct++) {
        sv[ct][0] = sT[rt][ct][0] * SC;
        sv[ct][1] = sT[rt][ct][1] * SC;
        sv[ct][2] = sT[rt][ct][2] * SC;
        sv[ct][3] = sT[rt][ct][3] * SC;
        tm = fmaxf(tm, mv4[ct].x ? sv[ct][0] : -3.0e38f);
        tm = fmaxf(tm, mv4[ct].y ? sv[ct][1] : -3.0e38f);
        tm = fmaxf(tm, mv4[ct].z ? sv[ct][2] : -3.0e38f);
        tm = fmaxf(tm, mv4[ct].w ? sv[ct][3] : -3.0e38f);
      }
      tm = fmaxf(tm, __shfl_xor(tm, 16));
      tm = fmaxf(tm, __shfl_xor(tm, 32));
      float mn = fmaxf(m_run[rt], tm);
      float corr = exp2f(m_run[rt] - mn);
      m_run[rt] = mn;
      float rs = 0.0f;
#pragma unroll
      for (int ct = 0; ct < 4; ct++) {
        float p0 = mv4[ct].x ? exp2f(sv[ct][0] - mn) : 0.0f;
        float p1 = mv4[ct].y ? exp2f(sv[ct][1] - mn) : 0.0f;
        float p2 = mv4[ct].z ? exp2f(sv[ct][2] - mn) : 0.0f;
        float p3 = mv4[ct].w ? exp2f(sv[ct][3] - mn) : 0.0f;
        rs += (p0 + p1) + (p2 + p3);
        uint2 pp;
        pp.x = pkbf(p0, p1);
        pp.y = pkbf(p2, p3);
        *(uint2*)(Pw + swz(rt * 16 + l15, ct * 16 + g * 4)) = pp;
      }
      rs += __shfl_xor(rs, 16);
      rs += __shfl_xor(rs, 32);
      l_run[rt] = l_run[rt] * corr + rs;
      // Rescale acc: corr is indexed by q=l15; acc rows are q=g*4+reg
      float ca[4];
#pragma unroll
      for (int reg = 0; reg < 4; reg++)
        ca[reg] = __builtin_bit_cast(
            float, __builtin_amdgcn_ds_bpermute(
                       corr_addr[reg], __builtin_bit_cast(int, corr)));
#pragma unroll
      for (int ht = 0; ht < 4; ht++)
#pragma unroll
        for (int reg = 0; reg < 4; reg++) acc[rt][ht][reg] *= ca[reg];
    }

    // O += P V (P from wave-private LDS as A-frags; V^T direct from global)
#pragma unroll
    for (int kk = 0; kk < 2; kk++) {
      bf16x8 pa[2];
#pragma unroll
      for (int rt = 0; rt < 2; rt++)
        pa[rt] = *(const bf16x8*)(Pw + swz(rt * 16 + l15, kk * 32 + g * 8));
#pragma unroll
      for (int ht = 0; ht < 4; ht++) {
        bf16x8 vf = *(const bf16x8*)(Vb + (size_t)(ht * 16 + l15) * NS + kv0 +
                                     kk * 32 + g * 8);
        acc[0][ht] = mfma16(pa[0], vf, acc[0][ht]);
        acc[1][ht] = mfma16(pa[1], vf, acc[1][ht]);
      }
    }
  }

  // Merge the 4 KV-chunk partials via LDS
  __syncthreads();  // all P-tiles dead; alias smem as accL/mlL
  float* accL = (float*)smem;            // [z][row][65] padded
  float* mlL = (float*)(smem + 33280);   // [z][row][2]
#pragma unroll
  for (int rt = 0; rt < 2; rt++) {
    int row = rt * 16 + g * 4;
#pragma unroll
    for (int ht = 0; ht < 4; ht++)
#pragma unroll
      for (int reg = 0; reg < 4; reg++)
        accL[(w * 32 + row + reg) * 65 + ht * 16 + l15] = acc[rt][ht][reg];
    if (lane < 16) {
      mlL[(w * 32 + rt * 16 + l15) * 2 + 0] = m_run[rt];
      mlL[(w * 32 + rt * 16 + l15) * 2 + 1] = l_run[rt];
    }
  }
  __syncthreads();

#pragma unroll
  for (int i = 0; i < 8; i++) {
    int idx = tid + i * 256;  // 0..2047
    int row = idx >> 6, h = idx & 63;
    float m[4], l[4];
#pragma unroll
    for (int z = 0; z < 4; z++) {
      m[z] = mlL[(z * 32 + row) * 2 + 0];
      l[z] = mlL[(z * 32 + row) * 2 + 1];
    }
    float M = fmaxf(fmaxf(m[0], m[1]), fmaxf(m[2], m[3]));
    float den = 0.0f, o = 0.0f;
#pragma unroll
    for (int z = 0; z < 4; z++) {
      float e = exp2f(m[z] - M);
      den += e * l[z];
      o += e * accL[(z * 32 + row) * 65 + h];
    }
    out[((size_t)b * NS + q0 + row) * NH + h] = o / den;
  }
}

extern "C" void kernel_launch(void* const* d_in, const int* in_sizes, int n_in,
                              void* d_out, int out_size, void* d_ws,
                              size_t ws_size, hipStream_t stream) {
  const float* inp = (const float*)d_in[0];
  const int* mask = (const int*)d_in[1];
  const float* Wq = (const float*)d_in[2];
  const float* bq = (const float*)d_in[3];
  const float* Wk = (const float*)d_in[4];
  const float* bk = (const float*)d_in[5];
  const float* Wv = (const float*)d_in[6];
  const float* bv = (const float*)d_in[7];
  float* out = (float*)d_out;

  char* ws = (char*)d_ws;
  u16* wsW = (u16*)ws;                          // 288 KB (frag-ordered weights)
  u16* wsQ = (u16*)(ws + (1u << 20));           // 4 MB
  u16* wsK = (u16*)(ws + (1u << 20) + (4u << 20));
  u16* wsVt = (u16*)(ws + (1u << 20) + (8u << 20));

  prep_weights<<<dim3(72), dim3(256), 0, stream>>>(Wq, Wk, Wv, wsW);
  qkv_proj<<<dim3((NB * NS) / 128), dim3(512), 0, stream>>>(inp, wsW, bq, bk,
                                                            bv, wsQ, wsK, wsVt);
  attn<<<dim3(NS / 32, NB), dim3(256), 0, stream>>>(wsQ, wsK, wsVt, mask, out);
}